// Round 13
// baseline (616.047 us; speedup 1.0000x reference)
//
#include <hip/hip_runtime.h>

// Graph-transformer MHA layer. N=50000, E=1600000, IN_DIM=64, H=8, D=8.
// Outputs: h_out [N*64] then e_out [E*64], fp32, concatenated in d_out.
//
// R13: edge kernel software-pipelined over 32-edge units.
//  Each wave grid-strides over units; while unit k computes, unit k+1's
//  e half-rows + indices are already in flight (sched_barrier(0) pins the
//  prefetch against sinking). Kills the per-wave cold-start stall on the
//  410MB e stream that made R12 latency-bound (VALU 12% ~= single-wave duty).
//  Rest identical to R12 (rank+offsets sorted scatter, coalesced aggregate).

using short8 = __attribute__((ext_vector_type(8))) short;
using f32x16 = __attribute__((ext_vector_type(16))) float;

__device__ __forceinline__ short f2bf(float f) {
    unsigned u = __builtin_bit_cast(unsigned, f);
    u += 0x7FFF + ((u >> 16) & 1);          // RNE to bf16
    return (short)(u >> 16);
}

// ---------------- node projection ----------------
__global__ __launch_bounds__(256)
void proj_kernel(const float* __restrict__ hsrc,
                 const float* __restrict__ Wq, const float* __restrict__ bq,
                 const float* __restrict__ Wk, const float* __restrict__ bk,
                 const float* __restrict__ Wv, const float* __restrict__ bv,
                 float* __restrict__ Q, float* __restrict__ K, float* __restrict__ V,
                 int n)
{
    const float* W;
    const float* b;
    float* out;
    if (blockIdx.y == 0)      { W = Wq; b = bq; out = Q; }
    else if (blockIdx.y == 1) { W = Wk; b = bk; out = K; }
    else                      { W = Wv; b = bv; out = V; }

    const int t    = threadIdx.x;
    const int lane = t & 63;
    const int w    = t >> 6;

    float wcol[64];
#pragma unroll
    for (int k = 0; k < 64; ++k) wcol[k] = W[k * 64 + lane];
    const float bias = b[lane];

    __shared__ float4 sh[16][16];
    const float4* __restrict__ h4 = (const float4*)hsrc;

    const int ngroups = (n + 15) >> 4;
    for (int g = blockIdx.x; g < ngroups; g += gridDim.x) {
        const int base = g << 4;
        {
            const int rs = t >> 4, c4 = t & 15;
            float4 v = make_float4(0.f, 0.f, 0.f, 0.f);
            if (base + rs < n) v = h4[(size_t)(base + rs) * 16 + c4];
            __syncthreads();
            sh[rs][c4] = v;
            __syncthreads();
        }
        float acc0 = bias, acc1 = bias, acc2 = bias, acc3 = bias;
#pragma unroll
        for (int k4 = 0; k4 < 16; ++k4) {
            const float w0 = wcol[k4 * 4 + 0], w1 = wcol[k4 * 4 + 1];
            const float w2 = wcol[k4 * 4 + 2], w3 = wcol[k4 * 4 + 3];
            const float4 a = sh[w * 4 + 0][k4];
            const float4 bb = sh[w * 4 + 1][k4];
            const float4 c = sh[w * 4 + 2][k4];
            const float4 d = sh[w * 4 + 3][k4];
            acc0 = fmaf(a.w,  w3, fmaf(a.z,  w2, fmaf(a.y,  w1, fmaf(a.x,  w0, acc0))));
            acc1 = fmaf(bb.w, w3, fmaf(bb.z, w2, fmaf(bb.y, w1, fmaf(bb.x, w0, acc1))));
            acc2 = fmaf(c.w,  w3, fmaf(c.z,  w2, fmaf(c.y,  w1, fmaf(c.x,  w0, acc2))));
            acc3 = fmaf(d.w,  w3, fmaf(d.z,  w2, fmaf(d.y,  w1, fmaf(d.x,  w0, acc3))));
        }
        const int n0 = base + w * 4;
        if (n0 + 0 < n) out[(size_t)(n0 + 0) * 64 + lane] = acc0;
        if (n0 + 1 < n) out[(size_t)(n0 + 1) * 64 + lane] = acc1;
        if (n0 + 2 < n) out[(size_t)(n0 + 2) * 64 + lane] = acc2;
        if (n0 + 3 < n) out[(size_t)(n0 + 3) * 64 + lane] = acc3;
    }
}

// ---------------- rank kernel: histogram + within-segment rank in ONE pass ----------------
__global__ __launch_bounds__(256)
void rank_kernel(const int* __restrict__ dst, int* __restrict__ counts,
                 int* __restrict__ rank, int E)
{
    int i = blockIdx.x * 256 + threadIdx.x;
    const int stride = gridDim.x * 256;
    for (; i < E; i += stride) {
        rank[i] = atomicAdd(&counts[dst[i]], 1);
    }
}

// ---------------- multi-block exclusive scan (3 kernels) ----------------
__global__ __launch_bounds__(1024)
void scan1_kernel(const int* __restrict__ counts, int* __restrict__ offsets,
                  int* __restrict__ bsum, int n)
{
    const int t = threadIdx.x;
    const int lane = t & 63;
    const int w = t >> 6;
    __shared__ int wsum[16];
    const int i = blockIdx.x * 1024 + t;
    const int v = (i < n) ? counts[i] : 0;
    int x = v;
#pragma unroll
    for (int d = 1; d < 64; d <<= 1) {
        int y = __shfl_up(x, d);
        if (lane >= d) x += y;
    }
    if (lane == 63) wsum[w] = x;
    __syncthreads();
    if (w == 0 && lane < 16) {
        int s = wsum[lane];
#pragma unroll
        for (int d = 1; d < 16; d <<= 1) {
            int y = __shfl_up(s, d);
            if (lane >= d) s += y;
        }
        wsum[lane] = s;
    }
    __syncthreads();
    const int excl = ((w == 0) ? 0 : wsum[w - 1]) + (x - v);
    if (i < n) offsets[i] = excl;
    if (t == 1023) bsum[blockIdx.x] = excl + v;
}

__global__ __launch_bounds__(64)
void scan2_kernel(int* __restrict__ bsum, int nb)
{
    const int lane = threadIdx.x;
    const int v = (lane < nb) ? bsum[lane] : 0;
    int x = v;
#pragma unroll
    for (int d = 1; d < 64; d <<= 1) {
        int y = __shfl_up(x, d);
        if (lane >= d) x += y;
    }
    if (lane < nb) bsum[lane] = x - v;   // exclusive
}

__global__ __launch_bounds__(1024)
void scan3_kernel(int* __restrict__ offsets, const int* __restrict__ bsum,
                  int n, int E)
{
    const int i = blockIdx.x * 1024 + threadIdx.x;
    if (i < n) offsets[i] += bsum[blockIdx.x];
    if (blockIdx.x == 0 && threadIdx.x == 0) offsets[n] = E;
}

// load one 32-edge unit's per-lane inputs: indices + e half-row (8 float4)
#define LOAD_UNIT(U, SE, DE, RK, P0,P1,P2,P3,P4,P5,P6,P7) do {            \
    const int _erow = (U) * 32 + lid;                                      \
    const int _erc  = _erow < E ? _erow : (E - 1);                         \
    SE = src[_erc]; DE = dst[_erc]; RK = rank[_erc];                       \
    const float* _er = e + (size_t)_erc * 64 + 4 * hi;                     \
    P0 = *(const float4*)(_er + 0);  P1 = *(const float4*)(_er + 8);       \
    P2 = *(const float4*)(_er + 16); P3 = *(const float4*)(_er + 24);      \
    P4 = *(const float4*)(_er + 32); P5 = *(const float4*)(_er + 40);      \
    P6 = *(const float4*)(_er + 48); P7 = *(const float4*)(_er + 56);      \
} while (0)

// ---------------- edge kernel v13: MFMA, unit pipeline ----------------
__global__ __launch_bounds__(256)
void edge_kernel(const float* __restrict__ e,
                 const float* __restrict__ We, const float* __restrict__ be,
                 const int* __restrict__ src, const int* __restrict__ dst,
                 const float* __restrict__ Q, const float* __restrict__ K,
                 float* __restrict__ e_out,
                 float* __restrict__ s_sorted, int* __restrict__ src_sorted,
                 const int* __restrict__ rank, const int* __restrict__ offs,
                 int E)
{
    __shared__ float4 tile4[4][32 * 8];             // 4KB per wave, XOR-swizzled
    const int t    = threadIdx.x;
    const int lane = t & 63;
    const int wu   = __builtin_amdgcn_readfirstlane(t >> 6);
    const int lid  = lane & 31;
    const int hi   = lane >> 5;
    float4* const myT4 = tile4[wu];
    const float inv = 0.35355339059327373f;         // 1/sqrt(8)

    // A fragments (We^T), loaded once per wave. A[jh][ks] elem (4g+i) holds
    // We[k = 16ks + 8g + 4hi + i][j = 32jh + lid].
    short8 Afr[2][4];
#pragma unroll
    for (int jh = 0; jh < 2; ++jh)
#pragma unroll
        for (int ks = 0; ks < 4; ++ks)
#pragma unroll
            for (int g = 0; g < 2; ++g)
#pragma unroll
                for (int i = 0; i < 4; ++i)
                    Afr[jh][ks][4 * g + i] =
                        f2bf(We[(16 * ks + 8 * g + 4 * hi + i) * 64 + 32 * jh + lid]);

    const int nunits  = (E + 31) >> 5;              // 32-edge units
    const int wstride = gridDim.x * 4;
    int u = blockIdx.x * 4 + wu;
    if (u >= nunits) return;

    int se, de, rkr;
    float4 p0, p1, p2, p3, p4, p5, p6, p7;
    LOAD_UNIT(u, se, de, rkr, p0, p1, p2, p3, p4, p5, p6, p7);

    for (;;) {
        // ---- prefetch next unit (pinned before compute) ----
        const int un = u + wstride;
        const int uc = un < nunits ? un : u;        // clamped: cheap L1 re-read at tail
        int se_n, de_n, rk_n;
        float4 n0, n1, n2, n3, n4, n5, n6, n7;
        LOAD_UNIT(uc, se_n, de_n, rk_n, n0, n1, n2, n3, n4, n5, n6, n7);
        __builtin_amdgcn_sched_barrier(0);

        // ---- compute current unit ----
        const int base32 = u * 32;
        const int erow   = base32 + lid;
        const bool valid = erow < E;
        const int rk = offs[de] + rkr;              // sorted slot (address only)

        // cvt B fragments: elem (4g+i) = e[row][k = 16ks + 8g + 4hi + i]
        short8 Bfr[4];
#pragma unroll
        for (int ks = 0; ks < 4; ++ks) {
            const float4 pa = (ks == 0) ? p0 : (ks == 1) ? p2 : (ks == 2) ? p4 : p6;
            const float4 pb = (ks == 0) ? p1 : (ks == 1) ? p3 : (ks == 2) ? p5 : p7;
            Bfr[ks][0] = f2bf(pa.x); Bfr[ks][1] = f2bf(pa.y);
            Bfr[ks][2] = f2bf(pa.z); Bfr[ks][3] = f2bf(pa.w);
            Bfr[ks][4] = f2bf(pb.x); Bfr[ks][5] = f2bf(pb.y);
            Bfr[ks][6] = f2bf(pb.z); Bfr[ks][7] = f2bf(pb.w);
        }

        float gate[8];
#pragma unroll
        for (int jh = 0; jh < 2; ++jh) {
            f32x16 D = {};
#pragma unroll
            for (int ks = 0; ks < 4; ++ks)
                D = __builtin_amdgcn_mfma_f32_32x32x16_bf16(
                        Afr[jh][ks], Bfr[ks], D, 0, 0, 0);

            // previous phase's LDS reads must be done before overwrite
            asm volatile("s_waitcnt lgkmcnt(0)" ::: "memory");

            // epilogue: JIT kv/qv/bev loads per hd; stage + head sums
            const float* kb = K + (size_t)se * 64 + 32 * jh + 4 * hi;
            const float* qb = Q + (size_t)de * 64 + 32 * jh + 4 * hi;
#pragma unroll
            for (int hd = 0; hd < 4; ++hd) {
                const float4 kv  = *(const float4*)(kb + 8 * hd);
                const float4 qv  = *(const float4*)(qb + 8 * hd);
                const float4 bev = *(const float4*)(be + 32 * jh + 8 * hd + 4 * hi);
                // reg r = 4*hd + i  ->  j_local(within jh) = 8*hd + 4*hi + i
                const float s0 = kv.x * qv.x * inv * (D[4 * hd + 0] + bev.x);
                const float s1 = kv.y * qv.y * inv * (D[4 * hd + 1] + bev.y);
                const float s2 = kv.z * qv.z * inv * (D[4 * hd + 2] + bev.z);
                const float s3 = kv.w * qv.w * inv * (D[4 * hd + 3] + bev.w);
                const int c4 = (2 * hd + hi) ^ (lid & 7);       // XOR swizzle
                myT4[lid * 8 + c4] = make_float4(s0, s1, s2, s3);
                float pp = (s0 + s1) + (s2 + s3);
                const float full = pp + __shfl_xor(pp, 32);     // head = 4jh+hd
                gate[jh * 4 + hd] = expf(fminf(fmaxf(full, -5.f), 5.f));
            }

            // readout: 4 x 64-lane dwordx4 stores of 128B half-rows
            const int r8 = lane >> 3, m = lane & 7;
#pragma unroll
            for (int it = 0; it < 4; ++it) {
                const int row = it * 8 + r8;                    // edge row 0..31
                const int edge2 = base32 + row;
                const float4 v = myT4[row * 8 + (m ^ (row & 7))];
                if (edge2 < E)
                    *((float4*)e_out + (size_t)edge2 * 16 + jh * 8 + m) = v;
            }
        }

        // rank-scattered gate + src writes (fire-and-forget)
        if (valid) {
            const float4 g = (hi == 0)
                ? make_float4(gate[0], gate[1], gate[2], gate[3])
                : make_float4(gate[4], gate[5], gate[6], gate[7]);
            *(float4*)(s_sorted + (size_t)rk * 8 + hi * 4) = g;
            if (hi == 0) src_sorted[rk] = se;
        }

        // ---- rotate pipeline ----
        if (un >= nunits) break;
        u = un; se = se_n; de = de_n; rkr = rk_n;
        p0 = n0; p1 = n1; p2 = n2; p3 = n3;
        p4 = n4; p5 = n5; p6 = n6; p7 = n7;
    }
}

// ---------------- aggregation: one wave per node, coalesced sorted reads ----------------
__global__ __launch_bounds__(256)
void aggregate_kernel(const int* __restrict__ offsets,
                      const int* __restrict__ src_sorted,
                      const float* __restrict__ s_sorted,
                      const float* __restrict__ V,
                      float* __restrict__ hout, int n)
{
    const int w = (blockIdx.x * 256 + threadIdx.x) >> 6;
    const int lane = threadIdx.x & 63;
    if (w >= n) return;
    const int o0 = offsets[w], o1 = offsets[w + 1];
    const int head = lane >> 3;
    float acc = 0.f, zacc = 0.f;
    int j = o0;
    for (; j + 4 <= o1; j += 4) {
        const int sv0 = src_sorted[j + 0];
        const int sv1 = src_sorted[j + 1];
        const int sv2 = src_sorted[j + 2];
        const int sv3 = src_sorted[j + 3];
        const float s0 = s_sorted[(size_t)(j + 0) * 8 + head];
        const float s1 = s_sorted[(size_t)(j + 1) * 8 + head];
        const float s2 = s_sorted[(size_t)(j + 2) * 8 + head];
        const float s3 = s_sorted[(size_t)(j + 3) * 8 + head];
        const float v0 = V[(size_t)sv0 * 64 + lane];
        const float v1 = V[(size_t)sv1 * 64 + lane];
        const float v2 = V[(size_t)sv2 * 64 + lane];
        const float v3 = V[(size_t)sv3 * 64 + lane];
        acc = fmaf(v0, s0, acc);
        acc = fmaf(v1, s1, acc);
        acc = fmaf(v2, s2, acc);
        acc = fmaf(v3, s3, acc);
        zacc += (s0 + s1) + (s2 + s3);
    }
    for (; j < o1; ++j) {
        const int sv = src_sorted[j];
        const float s = s_sorted[(size_t)j * 8 + head];
        acc = fmaf(V[(size_t)sv * 64 + lane], s, acc);
        zacc += s;
    }
    hout[(size_t)w * 64 + lane] = acc / (zacc + 1e-6f);
}

extern "C" void kernel_launch(void* const* d_in, const int* in_sizes, int n_in,
                              void* d_out, int out_size, void* d_ws, size_t ws_size,
                              hipStream_t stream)
{
    const float* h  = (const float*)d_in[0];
    const float* e  = (const float*)d_in[1];
    const float* Wq = (const float*)d_in[2];
    const float* bq = (const float*)d_in[3];
    const float* Wk = (const float*)d_in[4];
    const float* bk = (const float*)d_in[5];
    const float* Wv = (const float*)d_in[6];
    const float* bv = (const float*)d_in[7];
    const float* We = (const float*)d_in[8];
    const float* be = (const float*)d_in[9];
    const int* src  = (const int*)d_in[10];
    const int* dst  = (const int*)d_in[11];

    const int N = in_sizes[0] / 64;
    const int E = in_sizes[1] / 64;

    float* hout  = (float*)d_out;                    // [N*64]
    float* e_out = (float*)d_out + (size_t)N * 64;   // [E*64]

    // workspace layout
    char* ws = (char*)d_ws;
    float* Q = (float*)ws;                 ws += (size_t)N * 64 * sizeof(float);
    float* K = (float*)ws;                 ws += (size_t)N * 64 * sizeof(float);
    float* V = (float*)ws;                 ws += (size_t)N * 64 * sizeof(float);
    float* s_sorted = (float*)ws;          ws += (size_t)E * 8 * sizeof(float);
    int* src_sorted = (int*)ws;            ws += (size_t)E * sizeof(int);
    int* rank = (int*)ws;                  ws += (size_t)E * sizeof(int);
    int* counts  = (int*)ws;               ws += (size_t)N * sizeof(int);
    int* offsets = (int*)ws;               ws += (size_t)(N + 1) * sizeof(int);
    int* bsum    = (int*)ws;               ws += 64 * sizeof(int);

    hipMemsetAsync(counts, 0, (size_t)N * sizeof(int), stream);

    // 1) Q,K,V projections
    proj_kernel<<<dim3(512, 3), dim3(256), 0, stream>>>(
        h, Wq, bq, Wk, bk, Wv, bv, Q, K, V, N);

    // 2) histogram + rank in one pass
    rank_kernel<<<dim3(2048), dim3(256), 0, stream>>>(dst, counts, rank, E);

    // 3) exclusive scan -> offsets (multi-block, 3 kernels)
    const int nb = (N + 1023) / 1024;
    scan1_kernel<<<dim3(nb), dim3(1024), 0, stream>>>(counts, offsets, bsum, N);
    scan2_kernel<<<dim3(1), dim3(64), 0, stream>>>(bsum, nb);
    scan3_kernel<<<dim3(nb), dim3(1024), 0, stream>>>(offsets, bsum, N, E);

    // 4) edge pass: MFMA, unit-pipelined, rank-scattered gates
    edge_kernel<<<dim3(2048), dim3(256), 0, stream>>>(
        e, We, be, src, dst, Q, K, e_out, s_sorted, src_sorted, rank, offsets, E);

    // 5) aggregate per node (one wave each)
    const int ablocks = (N * 64 + 255) / 256;
    aggregate_kernel<<<dim3(ablocks), dim3(256), 0, stream>>>(
        offsets, src_sorted, s_sorted, V, hout, N);
}

// Round 14
// 580.346 us; speedup vs baseline: 1.0615x; 1.0615x over previous
//
#include <hip/hip_runtime.h>

// Graph-transformer MHA layer. N=50000, E=1600000, IN_DIM=64, H=8, D=8.
// Outputs: h_out [N*64] then e_out [E*64], fp32, concatenated in d_out.
//
// R14: recombination of best-measured components.
//  - edge kernel: EXACT R10 form (coalesced sg writes, no rank/offs/scatter)
//    - best measured 315us. (R12's inline scatter cost +65us inside the
//    latency-bound kernel; R13's source-level pipelining failed - compiler.)
//  - reorder kernel: NEW - reads sg/src/rank/dst coalesced, fire-and-forget
//    scatters to s_sorted/src_sorted. Pure streaming (~100MB), TLP-rich.
//  - aggregate: coalesced sorted reads (R12 form, ~100us).
//  - rank_kernel (hist+rank one pass) + 3-kernel scan unchanged.

using short8 = __attribute__((ext_vector_type(8))) short;
using f32x16 = __attribute__((ext_vector_type(16))) float;

__device__ __forceinline__ short f2bf(float f) {
    unsigned u = __builtin_bit_cast(unsigned, f);
    u += 0x7FFF + ((u >> 16) & 1);          // RNE to bf16
    return (short)(u >> 16);
}

// ---------------- node projection ----------------
__global__ __launch_bounds__(256)
void proj_kernel(const float* __restrict__ hsrc,
                 const float* __restrict__ Wq, const float* __restrict__ bq,
                 const float* __restrict__ Wk, const float* __restrict__ bk,
                 const float* __restrict__ Wv, const float* __restrict__ bv,
                 float* __restrict__ Q, float* __restrict__ K, float* __restrict__ V,
                 int n)
{
    const float* W;
    const float* b;
    float* out;
    if (blockIdx.y == 0)      { W = Wq; b = bq; out = Q; }
    else if (blockIdx.y == 1) { W = Wk; b = bk; out = K; }
    else                      { W = Wv; b = bv; out = V; }

    const int t    = threadIdx.x;
    const int lane = t & 63;
    const int w    = t >> 6;

    float wcol[64];
#pragma unroll
    for (int k = 0; k < 64; ++k) wcol[k] = W[k * 64 + lane];
    const float bias = b[lane];

    __shared__ float4 sh[16][16];
    const float4* __restrict__ h4 = (const float4*)hsrc;

    const int ngroups = (n + 15) >> 4;
    for (int g = blockIdx.x; g < ngroups; g += gridDim.x) {
        const int base = g << 4;
        {
            const int rs = t >> 4, c4 = t & 15;
            float4 v = make_float4(0.f, 0.f, 0.f, 0.f);
            if (base + rs < n) v = h4[(size_t)(base + rs) * 16 + c4];
            __syncthreads();
            sh[rs][c4] = v;
            __syncthreads();
        }
        float acc0 = bias, acc1 = bias, acc2 = bias, acc3 = bias;
#pragma unroll
        for (int k4 = 0; k4 < 16; ++k4) {
            const float w0 = wcol[k4 * 4 + 0], w1 = wcol[k4 * 4 + 1];
            const float w2 = wcol[k4 * 4 + 2], w3 = wcol[k4 * 4 + 3];
            const float4 a = sh[w * 4 + 0][k4];
            const float4 bb = sh[w * 4 + 1][k4];
            const float4 c = sh[w * 4 + 2][k4];
            const float4 d = sh[w * 4 + 3][k4];
            acc0 = fmaf(a.w,  w3, fmaf(a.z,  w2, fmaf(a.y,  w1, fmaf(a.x,  w0, acc0))));
            acc1 = fmaf(bb.w, w3, fmaf(bb.z, w2, fmaf(bb.y, w1, fmaf(bb.x, w0, acc1))));
            acc2 = fmaf(c.w,  w3, fmaf(c.z,  w2, fmaf(c.y,  w1, fmaf(c.x,  w0, acc2))));
            acc3 = fmaf(d.w,  w3, fmaf(d.z,  w2, fmaf(d.y,  w1, fmaf(d.x,  w0, acc3))));
        }
        const int n0 = base + w * 4;
        if (n0 + 0 < n) out[(size_t)(n0 + 0) * 64 + lane] = acc0;
        if (n0 + 1 < n) out[(size_t)(n0 + 1) * 64 + lane] = acc1;
        if (n0 + 2 < n) out[(size_t)(n0 + 2) * 64 + lane] = acc2;
        if (n0 + 3 < n) out[(size_t)(n0 + 3) * 64 + lane] = acc3;
    }
}

// ---------------- rank kernel: histogram + within-segment rank in ONE pass ----------------
__global__ __launch_bounds__(256)
void rank_kernel(const int* __restrict__ dst, int* __restrict__ counts,
                 int* __restrict__ rank, int E)
{
    int i = blockIdx.x * 256 + threadIdx.x;
    const int stride = gridDim.x * 256;
    for (; i < E; i += stride) {
        rank[i] = atomicAdd(&counts[dst[i]], 1);
    }
}

// ---------------- multi-block exclusive scan (3 kernels) ----------------
__global__ __launch_bounds__(1024)
void scan1_kernel(const int* __restrict__ counts, int* __restrict__ offsets,
                  int* __restrict__ bsum, int n)
{
    const int t = threadIdx.x;
    const int lane = t & 63;
    const int w = t >> 6;
    __shared__ int wsum[16];
    const int i = blockIdx.x * 1024 + t;
    const int v = (i < n) ? counts[i] : 0;
    int x = v;
#pragma unroll
    for (int d = 1; d < 64; d <<= 1) {
        int y = __shfl_up(x, d);
        if (lane >= d) x += y;
    }
    if (lane == 63) wsum[w] = x;
    __syncthreads();
    if (w == 0 && lane < 16) {
        int s = wsum[lane];
#pragma unroll
        for (int d = 1; d < 16; d <<= 1) {
            int y = __shfl_up(s, d);
            if (lane >= d) s += y;
        }
        wsum[lane] = s;
    }
    __syncthreads();
    const int excl = ((w == 0) ? 0 : wsum[w - 1]) + (x - v);
    if (i < n) offsets[i] = excl;
    if (t == 1023) bsum[blockIdx.x] = excl + v;
}

__global__ __launch_bounds__(64)
void scan2_kernel(int* __restrict__ bsum, int nb)
{
    const int lane = threadIdx.x;
    const int v = (lane < nb) ? bsum[lane] : 0;
    int x = v;
#pragma unroll
    for (int d = 1; d < 64; d <<= 1) {
        int y = __shfl_up(x, d);
        if (lane >= d) x += y;
    }
    if (lane < nb) bsum[lane] = x - v;   // exclusive
}

__global__ __launch_bounds__(1024)
void scan3_kernel(int* __restrict__ offsets, const int* __restrict__ bsum,
                  int n, int E)
{
    const int i = blockIdx.x * 1024 + threadIdx.x;
    if (i < n) offsets[i] += bsum[blockIdx.x];
    if (blockIdx.x == 0 && threadIdx.x == 0) offsets[n] = E;
}

// ---------------- edge kernel (R10 form): MFMA, no atomics, coalesced gates ----------------
__global__ __launch_bounds__(256)
void edge_kernel(const float* __restrict__ e,
                 const float* __restrict__ We, const float* __restrict__ be,
                 const int* __restrict__ src, const int* __restrict__ dst,
                 const float* __restrict__ Q, const float* __restrict__ K,
                 float* __restrict__ e_out, float* __restrict__ sg, int E)
{
    __shared__ float4 tile4[4][32 * 8];             // 4KB per wave, XOR-swizzled
    const int t    = threadIdx.x;
    const int lane = t & 63;
    const int wu   = __builtin_amdgcn_readfirstlane(t >> 6);
    const int lid  = lane & 31;
    const int hi   = lane >> 5;
    float4* const myT4 = tile4[wu];
    const float inv = 0.35355339059327373f;         // 1/sqrt(8)

    // A fragments (We^T), loaded once per wave. A[jh][ks] elem (4g+i) holds
    // We[k = 16ks + 8g + 4hi + i][j = 32jh + lid].
    short8 Afr[2][4];
#pragma unroll
    for (int jh = 0; jh < 2; ++jh)
#pragma unroll
        for (int ks = 0; ks < 4; ++ks)
#pragma unroll
            for (int g = 0; g < 2; ++g)
#pragma unroll
                for (int i = 0; i < 4; ++i)
                    Afr[jh][ks][4 * g + i] =
                        f2bf(We[(16 * ks + 8 * g + 4 * hi + i) * 64 + 32 * jh + lid]);

    const int ntiles = (E + 63) >> 6;
    for (int tb = blockIdx.x * 4 + wu; tb < ntiles; tb += gridDim.x * 4) {
        const int base = tb << 6;

#pragma unroll
        for (int eh = 0; eh < 2; ++eh) {
            const int erow_i = base + eh * 32 + lid;
            const int erc = erow_i < E ? erow_i : (E - 1);
            const int se = src[erc];
            const int de = dst[erc];

            // B fragments: elem (4g+i) = e[row][k = 16ks + 8g + 4hi + i]
            const float* er = e + (size_t)erc * 64 + 4 * hi;
            short8 Bfr[4];
#pragma unroll
            for (int ks = 0; ks < 4; ++ks) {
                const float4 p0 = *(const float4*)(er + 16 * ks);
                const float4 p1 = *(const float4*)(er + 16 * ks + 8);
                Bfr[ks][0] = f2bf(p0.x); Bfr[ks][1] = f2bf(p0.y);
                Bfr[ks][2] = f2bf(p0.z); Bfr[ks][3] = f2bf(p0.w);
                Bfr[ks][4] = f2bf(p1.x); Bfr[ks][5] = f2bf(p1.y);
                Bfr[ks][6] = f2bf(p1.z); Bfr[ks][7] = f2bf(p1.w);
            }

            float gate[8];
#pragma unroll
            for (int jh = 0; jh < 2; ++jh) {
                f32x16 D = {};
#pragma unroll
                for (int ks = 0; ks < 4; ++ks)
                    D = __builtin_amdgcn_mfma_f32_32x32x16_bf16(
                            Afr[jh][ks], Bfr[ks], D, 0, 0, 0);

                // previous phase's LDS reads must be done before overwrite
                asm volatile("s_waitcnt lgkmcnt(0)" ::: "memory");

                // epilogue: JIT kv/qv/bev loads per hd; stage + head sums
                const float* kb = K + (size_t)se * 64 + 32 * jh + 4 * hi;
                const float* qb = Q + (size_t)de * 64 + 32 * jh + 4 * hi;
#pragma unroll
                for (int hd = 0; hd < 4; ++hd) {
                    const float4 kv  = *(const float4*)(kb + 8 * hd);
                    const float4 qv  = *(const float4*)(qb + 8 * hd);
                    const float4 bev = *(const float4*)(be + 32 * jh + 8 * hd + 4 * hi);
                    // reg r = 4*hd + i  ->  j_local(within jh) = 8*hd + 4*hi + i
                    const float s0 = kv.x * qv.x * inv * (D[4 * hd + 0] + bev.x);
                    const float s1 = kv.y * qv.y * inv * (D[4 * hd + 1] + bev.y);
                    const float s2 = kv.z * qv.z * inv * (D[4 * hd + 2] + bev.z);
                    const float s3 = kv.w * qv.w * inv * (D[4 * hd + 3] + bev.w);
                    const int c4 = (2 * hd + hi) ^ (lid & 7);       // XOR swizzle
                    myT4[lid * 8 + c4] = make_float4(s0, s1, s2, s3);
                    float p = (s0 + s1) + (s2 + s3);
                    const float full = p + __shfl_xor(p, 32);       // head = 4jh+hd
                    gate[jh * 4 + hd] = expf(fminf(fmaxf(full, -5.f), 5.f));
                }

                // readout: 4 x 64-lane dwordx4 stores of 128B half-rows
                const int r8 = lane >> 3, m = lane & 7;
#pragma unroll
                for (int it = 0; it < 4; ++it) {
                    const int row = it * 8 + r8;                    // edge row 0..31
                    const int edge2 = base + eh * 32 + row;
                    const float4 v = myT4[row * 8 + (m ^ (row & 7))];
                    if (edge2 < E)
                        *((float4*)e_out + (size_t)edge2 * 16 + jh * 8 + m) = v;
                }
            }

            // coalesced gate write: 32 edges x 32B contiguous (1KB per phase)
            if (erow_i < E) {
                const float4 g = (hi == 0)
                    ? make_float4(gate[0], gate[1], gate[2], gate[3])
                    : make_float4(gate[4], gate[5], gate[6], gate[7]);
                *(float4*)(sg + (size_t)erow_i * 8 + hi * 4) = g;
            }
        }
    }
}

// ---------------- reorder kernel: coalesced read -> sorted scatter ----------------
__global__ __launch_bounds__(256)
void reorder_kernel(const float* __restrict__ sg, const int* __restrict__ src,
                    const int* __restrict__ dst, const int* __restrict__ rank,
                    const int* __restrict__ offs,
                    float* __restrict__ s_sorted, int* __restrict__ src_sorted,
                    int E)
{
    int i = blockIdx.x * 256 + threadIdx.x;
    const int stride = gridDim.x * 256;
    for (; i < E; i += stride) {
        const int rk = offs[dst[i]] + rank[i];
        const float4 g0 = *(const float4*)(sg + (size_t)i * 8);
        const float4 g1 = *(const float4*)(sg + (size_t)i * 8 + 4);
        *(float4*)(s_sorted + (size_t)rk * 8)     = g0;
        *(float4*)(s_sorted + (size_t)rk * 8 + 4) = g1;
        src_sorted[rk] = src[i];
    }
}

// ---------------- aggregation: one wave per node, coalesced sorted reads ----------------
__global__ __launch_bounds__(256)
void aggregate_kernel(const int* __restrict__ offsets,
                      const int* __restrict__ src_sorted,
                      const float* __restrict__ s_sorted,
                      const float* __restrict__ V,
                      float* __restrict__ hout, int n)
{
    const int w = (blockIdx.x * 256 + threadIdx.x) >> 6;
    const int lane = threadIdx.x & 63;
    if (w >= n) return;
    const int o0 = offsets[w], o1 = offsets[w + 1];
    const int head = lane >> 3;
    float acc = 0.f, zacc = 0.f;
    int j = o0;
    for (; j + 4 <= o1; j += 4) {
        const int sv0 = src_sorted[j + 0];
        const int sv1 = src_sorted[j + 1];
        const int sv2 = src_sorted[j + 2];
        const int sv3 = src_sorted[j + 3];
        const float s0 = s_sorted[(size_t)(j + 0) * 8 + head];
        const float s1 = s_sorted[(size_t)(j + 1) * 8 + head];
        const float s2 = s_sorted[(size_t)(j + 2) * 8 + head];
        const float s3 = s_sorted[(size_t)(j + 3) * 8 + head];
        const float v0 = V[(size_t)sv0 * 64 + lane];
        const float v1 = V[(size_t)sv1 * 64 + lane];
        const float v2 = V[(size_t)sv2 * 64 + lane];
        const float v3 = V[(size_t)sv3 * 64 + lane];
        acc = fmaf(v0, s0, acc);
        acc = fmaf(v1, s1, acc);
        acc = fmaf(v2, s2, acc);
        acc = fmaf(v3, s3, acc);
        zacc += (s0 + s1) + (s2 + s3);
    }
    for (; j < o1; ++j) {
        const int sv = src_sorted[j];
        const float s = s_sorted[(size_t)j * 8 + head];
        acc = fmaf(V[(size_t)sv * 64 + lane], s, acc);
        zacc += s;
    }
    hout[(size_t)w * 64 + lane] = acc / (zacc + 1e-6f);
}

extern "C" void kernel_launch(void* const* d_in, const int* in_sizes, int n_in,
                              void* d_out, int out_size, void* d_ws, size_t ws_size,
                              hipStream_t stream)
{
    const float* h  = (const float*)d_in[0];
    const float* e  = (const float*)d_in[1];
    const float* Wq = (const float*)d_in[2];
    const float* bq = (const float*)d_in[3];
    const float* Wk = (const float*)d_in[4];
    const float* bk = (const float*)d_in[5];
    const float* Wv = (const float*)d_in[6];
    const float* bv = (const float*)d_in[7];
    const float* We = (const float*)d_in[8];
    const float* be = (const float*)d_in[9];
    const int* src  = (const int*)d_in[10];
    const int* dst  = (const int*)d_in[11];

    const int N = in_sizes[0] / 64;
    const int E = in_sizes[1] / 64;

    float* hout  = (float*)d_out;                    // [N*64]
    float* e_out = (float*)d_out + (size_t)N * 64;   // [E*64]

    // workspace layout
    char* ws = (char*)d_ws;
    float* Q = (float*)ws;                 ws += (size_t)N * 64 * sizeof(float);
    float* K = (float*)ws;                 ws += (size_t)N * 64 * sizeof(float);
    float* V = (float*)ws;                 ws += (size_t)N * 64 * sizeof(float);
    float* sg = (float*)ws;                ws += (size_t)E * 8 * sizeof(float);
    float* s_sorted = (float*)ws;          ws += (size_t)E * 8 * sizeof(float);
    int* src_sorted = (int*)ws;            ws += (size_t)E * sizeof(int);
    int* rank = (int*)ws;                  ws += (size_t)E * sizeof(int);
    int* counts  = (int*)ws;               ws += (size_t)N * sizeof(int);
    int* offsets = (int*)ws;               ws += (size_t)(N + 1) * sizeof(int);
    int* bsum    = (int*)ws;               ws += 64 * sizeof(int);

    hipMemsetAsync(counts, 0, (size_t)N * sizeof(int), stream);

    // 1) Q,K,V projections
    proj_kernel<<<dim3(512, 3), dim3(256), 0, stream>>>(
        h, Wq, bq, Wk, bk, Wv, bv, Q, K, V, N);

    // 2) histogram + rank in one pass
    rank_kernel<<<dim3(2048), dim3(256), 0, stream>>>(dst, counts, rank, E);

    // 3) exclusive scan -> offsets (multi-block, 3 kernels)
    const int nb = (N + 1023) / 1024;
    scan1_kernel<<<dim3(nb), dim3(1024), 0, stream>>>(counts, offsets, bsum, N);
    scan2_kernel<<<dim3(1), dim3(64), 0, stream>>>(bsum, nb);
    scan3_kernel<<<dim3(nb), dim3(1024), 0, stream>>>(offsets, bsum, N, E);

    // 4) edge pass: MFMA, no atomics, coalesced gate writes (R10 form)
    const int ntiles = (E + 63) >> 6;
    const int eblocks = (ntiles + 3) / 4;           // 6250
    edge_kernel<<<dim3(eblocks), dim3(256), 0, stream>>>(
        e, We, be, src, dst, Q, K, e_out, sg, E);

    // 5) reorder: coalesced reads -> sorted scatter (TLP-rich)
    reorder_kernel<<<dim3(2048), dim3(256), 0, stream>>>(
        sg, src, dst, rank, offsets, s_sorted, src_sorted, E);

    // 6) aggregate per node (one wave each)
    const int ablocks = (N * 64 + 255) / 256;
    aggregate_kernel<<<dim3(ablocks), dim3(256), 0, stream>>>(
        offsets, src_sorted, s_sorted, V, hout, N);
}

// Round 15
// 565.874 us; speedup vs baseline: 1.0887x; 1.0256x over previous
//
#include <hip/hip_runtime.h>

// Graph-transformer MHA layer. N=50000, E=1600000, IN_DIM=64, H=8, D=8.
// Outputs: h_out [N*64] then e_out [E*64], fp32, concatenated in d_out.
//
// R15 (from R14):
//  - edge kernel: K/Q preloaded per eh (16 gathers in flight under cvt+MFMA
//    wall) instead of 8 serialized JIT stalls in the epilogue. Evidence:
//    R11 preload beat R12 JIT by 30us under identical scatter config.
//  - proj+rank fused into one kernel (blockIdx.y 0-2 proj, 3 rank) - they're
//    independent and resource-orthogonal; overlap saves ~20us.
//  - aggregate: 8-wide batching (more independent V-gathers in flight).
//  - reorder/scan unchanged (R14 form).

using short8 = __attribute__((ext_vector_type(8))) short;
using f32x16 = __attribute__((ext_vector_type(16))) float;

__device__ __forceinline__ short f2bf(float f) {
    unsigned u = __builtin_bit_cast(unsigned, f);
    u += 0x7FFF + ((u >> 16) & 1);          // RNE to bf16
    return (short)(u >> 16);
}

// ---------------- fused node projection (y=0..2) + rank (y=3) ----------------
__global__ __launch_bounds__(256)
void proj_rank_kernel(const float* __restrict__ hsrc,
                      const float* __restrict__ Wq, const float* __restrict__ bq,
                      const float* __restrict__ Wk, const float* __restrict__ bk,
                      const float* __restrict__ Wv, const float* __restrict__ bv,
                      float* __restrict__ Q, float* __restrict__ K, float* __restrict__ V,
                      const int* __restrict__ dst, int* __restrict__ counts,
                      int* __restrict__ rank, int n, int E)
{
    if (blockIdx.y == 3) {
        // rank path: histogram + within-segment rank in one pass
        int i = blockIdx.x * 256 + threadIdx.x;
        const int stride = gridDim.x * 256;
        for (; i < E; i += stride) {
            rank[i] = atomicAdd(&counts[dst[i]], 1);
        }
        return;
    }

    const float* W;
    const float* b;
    float* out;
    if (blockIdx.y == 0)      { W = Wq; b = bq; out = Q; }
    else if (blockIdx.y == 1) { W = Wk; b = bk; out = K; }
    else                      { W = Wv; b = bv; out = V; }

    const int t    = threadIdx.x;
    const int lane = t & 63;
    const int w    = t >> 6;

    float wcol[64];
#pragma unroll
    for (int k = 0; k < 64; ++k) wcol[k] = W[k * 64 + lane];
    const float bias = b[lane];

    __shared__ float4 sh[16][16];
    const float4* __restrict__ h4 = (const float4*)hsrc;

    const int ngroups = (n + 15) >> 4;
    for (int g = blockIdx.x; g < ngroups; g += gridDim.x) {
        const int base = g << 4;
        {
            const int rs = t >> 4, c4 = t & 15;
            float4 v = make_float4(0.f, 0.f, 0.f, 0.f);
            if (base + rs < n) v = h4[(size_t)(base + rs) * 16 + c4];
            __syncthreads();
            sh[rs][c4] = v;
            __syncthreads();
        }
        float acc0 = bias, acc1 = bias, acc2 = bias, acc3 = bias;
#pragma unroll
        for (int k4 = 0; k4 < 16; ++k4) {
            const float w0 = wcol[k4 * 4 + 0], w1 = wcol[k4 * 4 + 1];
            const float w2 = wcol[k4 * 4 + 2], w3 = wcol[k4 * 4 + 3];
            const float4 a = sh[w * 4 + 0][k4];
            const float4 bb = sh[w * 4 + 1][k4];
            const float4 c = sh[w * 4 + 2][k4];
            const float4 d = sh[w * 4 + 3][k4];
            acc0 = fmaf(a.w,  w3, fmaf(a.z,  w2, fmaf(a.y,  w1, fmaf(a.x,  w0, acc0))));
            acc1 = fmaf(bb.w, w3, fmaf(bb.z, w2, fmaf(bb.y, w1, fmaf(bb.x, w0, acc1))));
            acc2 = fmaf(c.w,  w3, fmaf(c.z,  w2, fmaf(c.y,  w1, fmaf(c.x,  w0, acc2))));
            acc3 = fmaf(d.w,  w3, fmaf(d.z,  w2, fmaf(d.y,  w1, fmaf(d.x,  w0, acc3))));
        }
        const int n0 = base + w * 4;
        if (n0 + 0 < n) out[(size_t)(n0 + 0) * 64 + lane] = acc0;
        if (n0 + 1 < n) out[(size_t)(n0 + 1) * 64 + lane] = acc1;
        if (n0 + 2 < n) out[(size_t)(n0 + 2) * 64 + lane] = acc2;
        if (n0 + 3 < n) out[(size_t)(n0 + 3) * 64 + lane] = acc3;
    }
}

// ---------------- multi-block exclusive scan (3 kernels) ----------------
__global__ __launch_bounds__(1024)
void scan1_kernel(const int* __restrict__ counts, int* __restrict__ offsets,
                  int* __restrict__ bsum, int n)
{
    const int t = threadIdx.x;
    const int lane = t & 63;
    const int w = t >> 6;
    __shared__ int wsum[16];
    const int i = blockIdx.x * 1024 + t;
    const int v = (i < n) ? counts[i] : 0;
    int x = v;
#pragma unroll
    for (int d = 1; d < 64; d <<= 1) {
        int y = __shfl_up(x, d);
        if (lane >= d) x += y;
    }
    if (lane == 63) wsum[w] = x;
    __syncthreads();
    if (w == 0 && lane < 16) {
        int s = wsum[lane];
#pragma unroll
        for (int d = 1; d < 16; d <<= 1) {
            int y = __shfl_up(s, d);
            if (lane >= d) s += y;
        }
        wsum[lane] = s;
    }
    __syncthreads();
    const int excl = ((w == 0) ? 0 : wsum[w - 1]) + (x - v);
    if (i < n) offsets[i] = excl;
    if (t == 1023) bsum[blockIdx.x] = excl + v;
}

__global__ __launch_bounds__(64)
void scan2_kernel(int* __restrict__ bsum, int nb)
{
    const int lane = threadIdx.x;
    const int v = (lane < nb) ? bsum[lane] : 0;
    int x = v;
#pragma unroll
    for (int d = 1; d < 64; d <<= 1) {
        int y = __shfl_up(x, d);
        if (lane >= d) x += y;
    }
    if (lane < nb) bsum[lane] = x - v;   // exclusive
}

__global__ __launch_bounds__(1024)
void scan3_kernel(int* __restrict__ offsets, const int* __restrict__ bsum,
                  int n, int E)
{
    const int i = blockIdx.x * 1024 + threadIdx.x;
    if (i < n) offsets[i] += bsum[blockIdx.x];
    if (blockIdx.x == 0 && threadIdx.x == 0) offsets[n] = E;
}

// ---------------- edge kernel v15: MFMA, K/Q preload, coalesced gates ----------------
__global__ __launch_bounds__(256)
void edge_kernel(const float* __restrict__ e,
                 const float* __restrict__ We, const float* __restrict__ be,
                 const int* __restrict__ src, const int* __restrict__ dst,
                 const float* __restrict__ Q, const float* __restrict__ K,
                 float* __restrict__ e_out, float* __restrict__ sg, int E)
{
    __shared__ float4 tile4[4][32 * 8];             // 4KB per wave, XOR-swizzled
    const int t    = threadIdx.x;
    const int lane = t & 63;
    const int wu   = __builtin_amdgcn_readfirstlane(t >> 6);
    const int lid  = lane & 31;
    const int hi   = lane >> 5;
    float4* const myT4 = tile4[wu];
    const float inv = 0.35355339059327373f;         // 1/sqrt(8)

    // A fragments (We^T), loaded once per wave. A[jh][ks] elem (4g+i) holds
    // We[k = 16ks + 8g + 4hi + i][j = 32jh + lid].
    short8 Afr[2][4];
#pragma unroll
    for (int jh = 0; jh < 2; ++jh)
#pragma unroll
        for (int ks = 0; ks < 4; ++ks)
#pragma unroll
            for (int g = 0; g < 2; ++g)
#pragma unroll
                for (int i = 0; i < 4; ++i)
                    Afr[jh][ks][4 * g + i] =
                        f2bf(We[(16 * ks + 8 * g + 4 * hi + i) * 64 + 32 * jh + lid]);

    const int ntiles = (E + 63) >> 6;
    for (int tb = blockIdx.x * 4 + wu; tb < ntiles; tb += gridDim.x * 4) {
        const int base = tb << 6;

#pragma unroll
        for (int eh = 0; eh < 2; ++eh) {
            const int erow_i = base + eh * 32 + lid;
            const int erc = erow_i < E ? erow_i : (E - 1);
            const int se = src[erc];
            const int de = dst[erc];

            // e row loads issued first
            const float* er = e + (size_t)erc * 64 + 4 * hi;
            float4 p0 = *(const float4*)(er + 0),  p1 = *(const float4*)(er + 8);
            float4 p2 = *(const float4*)(er + 16), p3 = *(const float4*)(er + 24);
            float4 p4 = *(const float4*)(er + 32), p5 = *(const float4*)(er + 40);
            float4 p6 = *(const float4*)(er + 48), p7 = *(const float4*)(er + 56);

            // K/Q rows for BOTH jh preloaded: 16 independent gathers in flight
            // under the cvt+MFMA wall (R11 evidence: -30us vs JIT epilogue)
            const float* kb = K + (size_t)se * 64 + 4 * hi;
            const float* qb = Q + (size_t)de * 64 + 4 * hi;
            float4 kv[2][4], qv[2][4];
#pragma unroll
            for (int jh = 0; jh < 2; ++jh)
#pragma unroll
                for (int hd = 0; hd < 4; ++hd) {
                    kv[jh][hd] = *(const float4*)(kb + 32 * jh + 8 * hd);
                    qv[jh][hd] = *(const float4*)(qb + 32 * jh + 8 * hd);
                }

            // cvt B fragments: elem (4g+i) = e[row][k = 16ks + 8g + 4hi + i]
            short8 Bfr[4];
#pragma unroll
            for (int ks = 0; ks < 4; ++ks) {
                const float4 pa = (ks == 0) ? p0 : (ks == 1) ? p2 : (ks == 2) ? p4 : p6;
                const float4 pb = (ks == 0) ? p1 : (ks == 1) ? p3 : (ks == 2) ? p5 : p7;
                Bfr[ks][0] = f2bf(pa.x); Bfr[ks][1] = f2bf(pa.y);
                Bfr[ks][2] = f2bf(pa.z); Bfr[ks][3] = f2bf(pa.w);
                Bfr[ks][4] = f2bf(pb.x); Bfr[ks][5] = f2bf(pb.y);
                Bfr[ks][6] = f2bf(pb.z); Bfr[ks][7] = f2bf(pb.w);
            }

            float gate[8];
#pragma unroll
            for (int jh = 0; jh < 2; ++jh) {
                f32x16 D = {};
#pragma unroll
                for (int ks = 0; ks < 4; ++ks)
                    D = __builtin_amdgcn_mfma_f32_32x32x16_bf16(
                            Afr[jh][ks], Bfr[ks], D, 0, 0, 0);

                // previous phase's LDS reads must be done before overwrite
                asm volatile("s_waitcnt lgkmcnt(0)" ::: "memory");

                // epilogue: preloaded kv/qv; stage + head sums
#pragma unroll
                for (int hd = 0; hd < 4; ++hd) {
                    const float4 bev = *(const float4*)(be + 32 * jh + 8 * hd + 4 * hi);
                    const float4 k4 = kv[jh][hd];
                    const float4 q4 = qv[jh][hd];
                    // reg r = 4*hd + i  ->  j_local(within jh) = 8*hd + 4*hi + i
                    const float s0 = k4.x * q4.x * inv * (D[4 * hd + 0] + bev.x);
                    const float s1 = k4.y * q4.y * inv * (D[4 * hd + 1] + bev.y);
                    const float s2 = k4.z * q4.z * inv * (D[4 * hd + 2] + bev.z);
                    const float s3 = k4.w * q4.w * inv * (D[4 * hd + 3] + bev.w);
                    const int c4 = (2 * hd + hi) ^ (lid & 7);       // XOR swizzle
                    myT4[lid * 8 + c4] = make_float4(s0, s1, s2, s3);
                    float pp = (s0 + s1) + (s2 + s3);
                    const float full = pp + __shfl_xor(pp, 32);     // head = 4jh+hd
                    gate[jh * 4 + hd] = expf(fminf(fmaxf(full, -5.f), 5.f));
                }

                // readout: 4 x 64-lane dwordx4 stores of 128B half-rows
                const int r8 = lane >> 3, m = lane & 7;
#pragma unroll
                for (int it = 0; it < 4; ++it) {
                    const int row = it * 8 + r8;                    // edge row 0..31
                    const int edge2 = base + eh * 32 + row;
                    const float4 v = myT4[row * 8 + (m ^ (row & 7))];
                    if (edge2 < E)
                        *((float4*)e_out + (size_t)edge2 * 16 + jh * 8 + m) = v;
                }
            }

            // coalesced gate write: 32 edges x 32B contiguous (1KB per phase)
            if (erow_i < E) {
                const float4 g = (hi == 0)
                    ? make_float4(gate[0], gate[1], gate[2], gate[3])
                    : make_float4(gate[4], gate[5], gate[6], gate[7]);
                *(float4*)(sg + (size_t)erow_i * 8 + hi * 4) = g;
            }
        }
    }
}

// ---------------- reorder kernel: coalesced read -> sorted scatter ----------------
__global__ __launch_bounds__(256)
void reorder_kernel(const float* __restrict__ sg, const int* __restrict__ src,
                    const int* __restrict__ dst, const int* __restrict__ rank,
                    const int* __restrict__ offs,
                    float* __restrict__ s_sorted, int* __restrict__ src_sorted,
                    int E)
{
    int i = blockIdx.x * 256 + threadIdx.x;
    const int stride = gridDim.x * 256;
    for (; i < E; i += stride) {
        const int rk = offs[dst[i]] + rank[i];
        const float4 g0 = *(const float4*)(sg + (size_t)i * 8);
        const float4 g1 = *(const float4*)(sg + (size_t)i * 8 + 4);
        *(float4*)(s_sorted + (size_t)rk * 8)     = g0;
        *(float4*)(s_sorted + (size_t)rk * 8 + 4) = g1;
        src_sorted[rk] = src[i];
    }
}

// ---------------- aggregation: one wave per node, 8-wide batching ----------------
__global__ __launch_bounds__(256)
void aggregate_kernel(const int* __restrict__ offsets,
                      const int* __restrict__ src_sorted,
                      const float* __restrict__ s_sorted,
                      const float* __restrict__ V,
                      float* __restrict__ hout, int n)
{
    const int w = (blockIdx.x * 256 + threadIdx.x) >> 6;
    const int lane = threadIdx.x & 63;
    if (w >= n) return;
    const int o0 = offsets[w], o1 = offsets[w + 1];
    const int head = lane >> 3;
    float acc = 0.f, zacc = 0.f;
    int j = o0;
    for (; j + 8 <= o1; j += 8) {
        int   sv[8];
        float ss[8];
#pragma unroll
        for (int q = 0; q < 8; ++q) {
            sv[q] = src_sorted[j + q];
            ss[q] = s_sorted[(size_t)(j + q) * 8 + head];
        }
        float vv[8];
#pragma unroll
        for (int q = 0; q < 8; ++q)
            vv[q] = V[(size_t)sv[q] * 64 + lane];
#pragma unroll
        for (int q = 0; q < 8; ++q) {
            acc = fmaf(vv[q], ss[q], acc);
            zacc += ss[q];
        }
    }
    for (; j < o1; ++j) {
        const int sv = src_sorted[j];
        const float s = s_sorted[(size_t)j * 8 + head];
        acc = fmaf(V[(size_t)sv * 64 + lane], s, acc);
        zacc += s;
    }
    hout[(size_t)w * 64 + lane] = acc / (zacc + 1e-6f);
}

extern "C" void kernel_launch(void* const* d_in, const int* in_sizes, int n_in,
                              void* d_out, int out_size, void* d_ws, size_t ws_size,
                              hipStream_t stream)
{
    const float* h  = (const float*)d_in[0];
    const float* e  = (const float*)d_in[1];
    const float* Wq = (const float*)d_in[2];
    const float* bq = (const float*)d_in[3];
    const float* Wk = (const float*)d_in[4];
    const float* bk = (const float*)d_in[5];
    const float* Wv = (const float*)d_in[6];
    const float* bv = (const float*)d_in[7];
    const float* We = (const float*)d_in[8];
    const float* be = (const float*)d_in[9];
    const int* src  = (const int*)d_in[10];
    const int* dst  = (const int*)d_in[11];

    const int N = in_sizes[0] / 64;
    const int E = in_sizes[1] / 64;

    float* hout  = (float*)d_out;                    // [N*64]
    float* e_out = (float*)d_out + (size_t)N * 64;   // [E*64]

    // workspace layout
    char* ws = (char*)d_ws;
    float* Q = (float*)ws;                 ws += (size_t)N * 64 * sizeof(float);
    float* K = (float*)ws;                 ws += (size_t)N * 64 * sizeof(float);
    float* V = (float*)ws;                 ws += (size_t)N * 64 * sizeof(float);
    float* sg = (float*)ws;                ws += (size_t)E * 8 * sizeof(float);
    float* s_sorted = (float*)ws;          ws += (size_t)E * 8 * sizeof(float);
    int* src_sorted = (int*)ws;            ws += (size_t)E * sizeof(int);
    int* rank = (int*)ws;                  ws += (size_t)E * sizeof(int);
    int* counts  = (int*)ws;               ws += (size_t)N * sizeof(int);
    int* offsets = (int*)ws;               ws += (size_t)(N + 1) * sizeof(int);
    int* bsum    = (int*)ws;               ws += 64 * sizeof(int);

    hipMemsetAsync(counts, 0, (size_t)N * sizeof(int), stream);

    // 1) fused Q,K,V projections + rank (independent, overlapped)
    proj_rank_kernel<<<dim3(512, 4), dim3(256), 0, stream>>>(
        h, Wq, bq, Wk, bk, Wv, bv, Q, K, V, dst, counts, rank, N, E);

    // 2) exclusive scan -> offsets (multi-block, 3 kernels)
    const int nb = (N + 1023) / 1024;
    scan1_kernel<<<dim3(nb), dim3(1024), 0, stream>>>(counts, offsets, bsum, N);
    scan2_kernel<<<dim3(1), dim3(64), 0, stream>>>(bsum, nb);
    scan3_kernel<<<dim3(nb), dim3(1024), 0, stream>>>(offsets, bsum, N, E);

    // 3) edge pass: MFMA, K/Q preload, coalesced gate writes
    const int ntiles = (E + 63) >> 6;
    const int eblocks = (ntiles + 3) / 4;           // 6250
    edge_kernel<<<dim3(eblocks), dim3(256), 0, stream>>>(
        e, We, be, src, dst, Q, K, e_out, sg, E);

    // 4) reorder: coalesced reads -> sorted scatter (TLP-rich)
    reorder_kernel<<<dim3(2048), dim3(256), 0, stream>>>(
        sg, src, dst, rank, offsets, s_sorted, src_sorted, E);

    // 5) aggregate per node (one wave each, 8-wide)
    const int ablocks = (N * 64 + 255) / 256;
    aggregate_kernel<<<dim3(ablocks), dim3(256), 0, stream>>>(
        offsets, src_sorted, s_sorted, V, hout, N);
}

// Round 16
// 533.565 us; speedup vs baseline: 1.1546x; 1.0606x over previous
//
#include <hip/hip_runtime.h>
#include <hip/hip_bf16.h>

// Graph-transformer MHA layer. N=50000, E=1600000, IN_DIM=64, H=8, D=8.
// Outputs: h_out [N*64] then e_out [E*64], fp32, concatenated in d_out.
//
// R16 (from R15):
//  - edge kernel: per-wave LDS tile DOUBLE-BUFFERED (2x4KB); the four hard
//    lgkmcnt(0) drains per tile are removed. WAR distance on each buffer is
//    now 2 phases, so the compiler inserts only counted waits and can hoist
//    eh1's loads under eh0's compute/readout. (R15's single tile + full
//    drains serialized all 4 phases - the residual latency chain.)
//  - f2bf via __float2bfloat16 casts (compiler fuses to v_cvt_pk_bf16_f32;
//    the old bit-math RNE couldn't be pattern-matched, ~4 VALU/value).
//  - everything else = R15 (proj+rank fused, 3-kernel scan, reorder,
//    8-wide aggregate).

using short8 = __attribute__((ext_vector_type(8))) short;
using f32x16 = __attribute__((ext_vector_type(16))) float;

__device__ __forceinline__ short f2bf(float f) {
    __hip_bfloat16 b = __float2bfloat16(f);     // RNE; pairs fuse to v_cvt_pk_bf16_f32
    return __builtin_bit_cast(short, b);
}

// ---------------- fused node projection (y=0..2) + rank (y=3) ----------------
__global__ __launch_bounds__(256)
void proj_rank_kernel(const float* __restrict__ hsrc,
                      const float* __restrict__ Wq, const float* __restrict__ bq,
                      const float* __restrict__ Wk, const float* __restrict__ bk,
                      const float* __restrict__ Wv, const float* __restrict__ bv,
                      float* __restrict__ Q, float* __restrict__ K, float* __restrict__ V,
                      const int* __restrict__ dst, int* __restrict__ counts,
                      int* __restrict__ rank, int n, int E)
{
    if (blockIdx.y == 3) {
        int i = blockIdx.x * 256 + threadIdx.x;
        const int stride = gridDim.x * 256;
        for (; i < E; i += stride) {
            rank[i] = atomicAdd(&counts[dst[i]], 1);
        }
        return;
    }

    const float* W;
    const float* b;
    float* out;
    if (blockIdx.y == 0)      { W = Wq; b = bq; out = Q; }
    else if (blockIdx.y == 1) { W = Wk; b = bk; out = K; }
    else                      { W = Wv; b = bv; out = V; }

    const int t    = threadIdx.x;
    const int lane = t & 63;
    const int w    = t >> 6;

    float wcol[64];
#pragma unroll
    for (int k = 0; k < 64; ++k) wcol[k] = W[k * 64 + lane];
    const float bias = b[lane];

    __shared__ float4 sh[16][16];
    const float4* __restrict__ h4 = (const float4*)hsrc;

    const int ngroups = (n + 15) >> 4;
    for (int g = blockIdx.x; g < ngroups; g += gridDim.x) {
        const int base = g << 4;
        {
            const int rs = t >> 4, c4 = t & 15;
            float4 v = make_float4(0.f, 0.f, 0.f, 0.f);
            if (base + rs < n) v = h4[(size_t)(base + rs) * 16 + c4];
            __syncthreads();
            sh[rs][c4] = v;
            __syncthreads();
        }
        float acc0 = bias, acc1 = bias, acc2 = bias, acc3 = bias;
#pragma unroll
        for (int k4 = 0; k4 < 16; ++k4) {
            const float w0 = wcol[k4 * 4 + 0], w1 = wcol[k4 * 4 + 1];
            const float w2 = wcol[k4 * 4 + 2], w3 = wcol[k4 * 4 + 3];
            const float4 a = sh[w * 4 + 0][k4];
            const float4 bb = sh[w * 4 + 1][k4];
            const float4 c = sh[w * 4 + 2][k4];
            const float4 d = sh[w * 4 + 3][k4];
            acc0 = fmaf(a.w,  w3, fmaf(a.z,  w2, fmaf(a.y,  w1, fmaf(a.x,  w0, acc0))));
            acc1 = fmaf(bb.w, w3, fmaf(bb.z, w2, fmaf(bb.y, w1, fmaf(bb.x, w0, acc1))));
            acc2 = fmaf(c.w,  w3, fmaf(c.z,  w2, fmaf(c.y,  w1, fmaf(c.x,  w0, acc2))));
            acc3 = fmaf(d.w,  w3, fmaf(d.z,  w2, fmaf(d.y,  w1, fmaf(d.x,  w0, acc3))));
        }
        const int n0 = base + w * 4;
        if (n0 + 0 < n) out[(size_t)(n0 + 0) * 64 + lane] = acc0;
        if (n0 + 1 < n) out[(size_t)(n0 + 1) * 64 + lane] = acc1;
        if (n0 + 2 < n) out[(size_t)(n0 + 2) * 64 + lane] = acc2;
        if (n0 + 3 < n) out[(size_t)(n0 + 3) * 64 + lane] = acc3;
    }
}

// ---------------- multi-block exclusive scan (3 kernels) ----------------
__global__ __launch_bounds__(1024)
void scan1_kernel(const int* __restrict__ counts, int* __restrict__ offsets,
                  int* __restrict__ bsum, int n)
{
    const int t = threadIdx.x;
    const int lane = t & 63;
    const int w = t >> 6;
    __shared__ int wsum[16];
    const int i = blockIdx.x * 1024 + t;
    const int v = (i < n) ? counts[i] : 0;
    int x = v;
#pragma unroll
    for (int d = 1; d < 64; d <<= 1) {
        int y = __shfl_up(x, d);
        if (lane >= d) x += y;
    }
    if (lane == 63) wsum[w] = x;
    __syncthreads();
    if (w == 0 && lane < 16) {
        int s = wsum[lane];
#pragma unroll
        for (int d = 1; d < 16; d <<= 1) {
            int y = __shfl_up(s, d);
            if (lane >= d) s += y;
        }
        wsum[lane] = s;
    }
    __syncthreads();
    const int excl = ((w == 0) ? 0 : wsum[w - 1]) + (x - v);
    if (i < n) offsets[i] = excl;
    if (t == 1023) bsum[blockIdx.x] = excl + v;
}

__global__ __launch_bounds__(64)
void scan2_kernel(int* __restrict__ bsum, int nb)
{
    const int lane = threadIdx.x;
    const int v = (lane < nb) ? bsum[lane] : 0;
    int x = v;
#pragma unroll
    for (int d = 1; d < 64; d <<= 1) {
        int y = __shfl_up(x, d);
        if (lane >= d) x += y;
    }
    if (lane < nb) bsum[lane] = x - v;   // exclusive
}

__global__ __launch_bounds__(1024)
void scan3_kernel(int* __restrict__ offsets, const int* __restrict__ bsum,
                  int n, int E)
{
    const int i = blockIdx.x * 1024 + threadIdx.x;
    if (i < n) offsets[i] += bsum[blockIdx.x];
    if (blockIdx.x == 0 && threadIdx.x == 0) offsets[n] = E;
}

// ---------------- edge kernel v16: MFMA, dbuf LDS, K/Q preload ----------------
__global__ __launch_bounds__(256)
void edge_kernel(const float* __restrict__ e,
                 const float* __restrict__ We, const float* __restrict__ be,
                 const int* __restrict__ src, const int* __restrict__ dst,
                 const float* __restrict__ Q, const float* __restrict__ K,
                 float* __restrict__ e_out, float* __restrict__ sg, int E)
{
    __shared__ float4 tile4[4][2][32 * 8];          // 2x4KB per wave, XOR-swizzled
    const int t    = threadIdx.x;
    const int lane = t & 63;
    const int wu   = __builtin_amdgcn_readfirstlane(t >> 6);
    const int lid  = lane & 31;
    const int hi   = lane >> 5;
    const float inv = 0.35355339059327373f;         // 1/sqrt(8)

    // A fragments (We^T), loaded once per wave. A[jh][ks] elem (4g+i) holds
    // We[k = 16ks + 8g + 4hi + i][j = 32jh + lid].
    short8 Afr[2][4];
#pragma unroll
    for (int jh = 0; jh < 2; ++jh)
#pragma unroll
        for (int ks = 0; ks < 4; ++ks)
#pragma unroll
            for (int g = 0; g < 2; ++g)
#pragma unroll
                for (int i = 0; i < 4; ++i)
                    Afr[jh][ks][4 * g + i] =
                        f2bf(We[(16 * ks + 8 * g + 4 * hi + i) * 64 + 32 * jh + lid]);

    const int ntiles = (E + 63) >> 6;
    for (int tb = blockIdx.x * 4 + wu; tb < ntiles; tb += gridDim.x * 4) {
        const int base = tb << 6;

#pragma unroll
        for (int eh = 0; eh < 2; ++eh) {
            const int erow_i = base + eh * 32 + lid;
            const int erc = erow_i < E ? erow_i : (E - 1);
            const int se = src[erc];
            const int de = dst[erc];

            // e row loads issued first
            const float* er = e + (size_t)erc * 64 + 4 * hi;
            float4 p0 = *(const float4*)(er + 0),  p1 = *(const float4*)(er + 8);
            float4 p2 = *(const float4*)(er + 16), p3 = *(const float4*)(er + 24);
            float4 p4 = *(const float4*)(er + 32), p5 = *(const float4*)(er + 40);
            float4 p6 = *(const float4*)(er + 48), p7 = *(const float4*)(er + 56);

            // K/Q rows for BOTH jh preloaded (16 independent gathers in flight)
            const float* kb = K + (size_t)se * 64 + 4 * hi;
            const float* qb = Q + (size_t)de * 64 + 4 * hi;
            float4 kv[2][4], qv[2][4];
#pragma unroll
            for (int jh = 0; jh < 2; ++jh)
#pragma unroll
                for (int hd = 0; hd < 4; ++hd) {
                    kv[jh][hd] = *(const float4*)(kb + 32 * jh + 8 * hd);
                    qv[jh][hd] = *(const float4*)(qb + 32 * jh + 8 * hd);
                }

            // cvt B fragments: elem (4g+i) = e[row][k = 16ks + 8g + 4hi + i]
            short8 Bfr[4];
#pragma unroll
            for (int ks = 0; ks < 4; ++ks) {
                const float4 pa = (ks == 0) ? p0 : (ks == 1) ? p2 : (ks == 2) ? p4 : p6;
                const float4 pb = (ks == 0) ? p1 : (ks == 1) ? p3 : (ks == 2) ? p5 : p7;
                Bfr[ks][0] = f2bf(pa.x); Bfr[ks][1] = f2bf(pa.y);
                Bfr[ks][2] = f2bf(pa.z); Bfr[ks][3] = f2bf(pa.w);
                Bfr[ks][4] = f2bf(pb.x); Bfr[ks][5] = f2bf(pb.y);
                Bfr[ks][6] = f2bf(pb.z); Bfr[ks][7] = f2bf(pb.w);
            }

            float gate[8];
#pragma unroll
            for (int jh = 0; jh < 2; ++jh) {
                // phase buffer: alternates each (eh,jh) phase -> WAR distance 2
                float4* const buf = tile4[wu][jh];

                f32x16 D = {};
#pragma unroll
                for (int ks = 0; ks < 4; ++ks)
                    D = __builtin_amdgcn_mfma_f32_32x32x16_bf16(
                            Afr[jh][ks], Bfr[ks], D, 0, 0, 0);

                // epilogue: preloaded kv/qv; stage + head sums
#pragma unroll
                for (int hd = 0; hd < 4; ++hd) {
                    const float4 bev = *(const float4*)(be + 32 * jh + 8 * hd + 4 * hi);
                    const float4 k4 = kv[jh][hd];
                    const float4 q4 = qv[jh][hd];
                    // reg r = 4*hd + i  ->  j_local(within jh) = 8*hd + 4*hi + i
                    const float s0 = k4.x * q4.x * inv * (D[4 * hd + 0] + bev.x);
                    const float s1 = k4.y * q4.y * inv * (D[4 * hd + 1] + bev.y);
                    const float s2 = k4.z * q4.z * inv * (D[4 * hd + 2] + bev.z);
                    const float s3 = k4.w * q4.w * inv * (D[4 * hd + 3] + bev.w);
                    const int c4 = (2 * hd + hi) ^ (lid & 7);       // XOR swizzle
                    buf[lid * 8 + c4] = make_float4(s0, s1, s2, s3);
                    float pp = (s0 + s1) + (s2 + s3);
                    const float full = pp + __shfl_xor(pp, 32);     // head = 4jh+hd
                    gate[jh * 4 + hd] = expf(fminf(fmaxf(full, -5.f), 5.f));
                }

                // readout: 4 x 64-lane dwordx4 stores of 128B half-rows
                // (compiler inserts the counted lgkm waits for buf deps)
                const int r8 = lane >> 3, m = lane & 7;
#pragma unroll
                for (int it = 0; it < 4; ++it) {
                    const int row = it * 8 + r8;                    // edge row 0..31
                    const int edge2 = base + eh * 32 + row;
                    const float4 v = buf[row * 8 + (m ^ (row & 7))];
                    if (edge2 < E)
                        *((float4*)e_out + (size_t)edge2 * 16 + jh * 8 + m) = v;
                }
            }

            // coalesced gate write: 32 edges x 32B contiguous (1KB per phase)
            if (erow_i < E) {
                const float4 g = (hi == 0)
                    ? make_float4(gate[0], gate[1], gate[2], gate[3])
                    : make_float4(gate[4], gate[5], gate[6], gate[7]);
                *(float4*)(sg + (size_t)erow_i * 8 + hi * 4) = g;
            }
        }
    }
}

// ---------------- reorder kernel: coalesced read -> sorted scatter ----------------
__global__ __launch_bounds__(256)
void reorder_kernel(const float* __restrict__ sg, const int* __restrict__ src,
                    const int* __restrict__ dst, const int* __restrict__ rank,
                    const int* __restrict__ offs,
                    float* __restrict__ s_sorted, int* __restrict__ src_sorted,
                    int E)
{
    int i = blockIdx.x * 256 + threadIdx.x;
    const int stride = gridDim.x * 256;
    for (; i < E; i += stride) {
        const int rk = offs[dst[i]] + rank[i];
        const float4 g0 = *(const float4*)(sg + (size_t)i * 8);
        const float4 g1 = *(const float4*)(sg + (size_t)i * 8 + 4);
        *(float4*)(s_sorted + (size_t)rk * 8)     = g0;
        *(float4*)(s_sorted + (size_t)rk * 8 + 4) = g1;
        src_sorted[rk] = src[i];
    }
}

// ---------------- aggregation: one wave per node, 8-wide batching ----------------
__global__ __launch_bounds__(256)
void aggregate_kernel(const int* __restrict__ offsets,
                      const int* __restrict__ src_sorted,
                      const float* __restrict__ s_sorted,
                      const float* __restrict__ V,
                      float* __restrict__ hout, int n)
{
    const int w = (blockIdx.x * 256 + threadIdx.x) >> 6;
    const int lane = threadIdx.x & 63;
    if (w >= n) return;
    const int o0 = offsets[w], o1 = offsets[w + 1];
    const int head = lane >> 3;
    float acc = 0.f, zacc = 0.f;
    int j = o0;
    for (; j + 8 <= o1; j += 8) {
        int   sv[8];
        float ss[8];
#pragma unroll
        for (int q = 0; q < 8; ++q) {
            sv[q] = src_sorted[j + q];
            ss[q] = s_sorted[(size_t)(j + q) * 8 + head];
        }
        float vv[8];
#pragma unroll
        for (int q = 0; q < 8; ++q)
            vv[q] = V[(size_t)sv[q] * 64 + lane];
#pragma unroll
        for (int q = 0; q < 8; ++q) {
            acc = fmaf(vv[q], ss[q], acc);
            zacc += ss[q];
        }
    }
    for (; j < o1; ++j) {
        const int sv = src_sorted[j];
        const float s = s_sorted[(size_t)j * 8 + head];
        acc = fmaf(V[(size_t)sv * 64 + lane], s, acc);
        zacc += s;
    }
    hout[(size_t)w * 64 + lane] = acc / (zacc + 1e-6f);
}

extern "C" void kernel_launch(void* const* d_in, const int* in_sizes, int n_in,
                              void* d_out, int out_size, void* d_ws, size_t ws_size,
                              hipStream_t stream)
{
    const float* h  = (const float*)d_in[0];
    const float* e  = (const float*)d_in[1];
    const float* Wq = (const float*)d_in[2];
    const float* bq = (const float*)d_in[3];
    const float* Wk = (const float*)d_in[4];
    const float* bk = (const float*)d_in[5];
    const float* Wv = (const float*)d_in[6];
    const float* bv = (const float*)d_in[7];
    const float* We = (const float*)d_in[8];
    const float* be = (const float*)d_in[9];
    const int* src  = (const int*)d_in[10];
    const int* dst  = (const int*)d_in[11];

    const int N = in_sizes[0] / 64;
    const int E = in_sizes[1] / 64;

    float* hout  = (float*)d_out;                    // [N*64]
    float* e_out = (float*)d_out + (size_t)N * 64;   // [E*64]

    // workspace layout
    char* ws = (char*)d_ws;
    float* Q = (float*)ws;                 ws += (size_t)N * 64 * sizeof(float);
    float* K = (float*)ws;                 ws += (size_t)N * 64 * sizeof(float);
    float* V = (float*)ws;                 ws += (size_t)N * 64 * sizeof(float);
    float* sg = (float*)ws;                ws += (size_t)E * 8 * sizeof(float);
    float* s_sorted = (float*)ws;          ws += (size_t)E * 8 * sizeof(float);
    int* src_sorted = (int*)ws;            ws += (size_t)E * sizeof(int);
    int* rank = (int*)ws;                  ws += (size_t)E * sizeof(int);
    int* counts  = (int*)ws;               ws += (size_t)N * sizeof(int);
    int* offsets = (int*)ws;               ws += (size_t)(N + 1) * sizeof(int);
    int* bsum    = (int*)ws;               ws += 64 * sizeof(int);

    hipMemsetAsync(counts, 0, (size_t)N * sizeof(int), stream);

    // 1) fused Q,K,V projections + rank (independent, overlapped)
    proj_rank_kernel<<<dim3(512, 4), dim3(256), 0, stream>>>(
        h, Wq, bq, Wk, bk, Wv, bv, Q, K, V, dst, counts, rank, N, E);

    // 2) exclusive scan -> offsets (multi-block, 3 kernels)
    const int nb = (N + 1023) / 1024;
    scan1_kernel<<<dim3(nb), dim3(1024), 0, stream>>>(counts, offsets, bsum, N);
    scan2_kernel<<<dim3(1), dim3(64), 0, stream>>>(bsum, nb);
    scan3_kernel<<<dim3(nb), dim3(1024), 0, stream>>>(offsets, bsum, N, E);

    // 3) edge pass: MFMA, dbuf LDS, K/Q preload, coalesced gate writes
    const int ntiles = (E + 63) >> 6;
    const int eblocks = (ntiles + 3) / 4;           // 6250
    edge_kernel<<<dim3(eblocks), dim3(256), 0, stream>>>(
        e, We, be, src, dst, Q, K, e_out, sg, E);

    // 4) reorder: coalesced reads -> sorted scatter (TLP-rich)
    reorder_kernel<<<dim3(2048), dim3(256), 0, stream>>>(
        sg, src, dst, rank, offsets, s_sorted, src_sorted, E);

    // 5) aggregate per node (one wave each, 8-wide)
    const int ablocks = (N * 64 + 255) / 256;
    aggregate_kernel<<<dim3(ablocks), dim3(256), 0, stream>>>(
        offsets, src_sorted, s_sorted, V, hout, N);
}